// Round 8
// baseline (802.629 us; speedup 1.0000x reference)
//
#include <hip/hip_runtime.h>
#include <hip/hip_cooperative_groups.h>

namespace cg = cooperative_groups;

// Problem constants
constexpr int   kAtoms  = 5000;
constexpr int   kPairs  = 160000;
constexpr int   KD      = 128;   // K
constexpr int   NB      = 8;     // N_BASIS
constexpr int   RH      = 32;    // RAD_HIDDEN
constexpr float kCutoff = 5.0f;
constexpr float kPi     = 3.14159265358979323846f;
constexpr float C1 = 0.2f * 0.1767767f;   // INIT_SCALE * MSG_SCALE
constexpr float C2 = 1.2f * 0.1767767f;   // (1+INIT_SCALE) * MSG_SCALE
constexpr int   TPB    = 256;
constexpr int   BLOCKS = 512;             // 2 blocks/CU — cooperative-safe

__device__ __forceinline__ float silu(float x) { return x / (1.0f + __expf(-x)); }

// Only the l=0 channel reaches the output; l>=1 / sph / U2 are dead code.
// One cooperative kernel, phases separated by grid.sync():
//   P0 zero cnt/wk | P1 hist | P2 scan (block 0) | P3 build: rbf,h2,nbrs,specs
//   P4 f0: G0 (species-factored, h1 inline from rbf)
//   P5 d0: V  (h2 via wave-uniform scalar reads, float2 G0 gathers)
//   P6 head MLP
struct Params {
    const float *pos, *cells;
    const int   *species, *shifts, *ctr, *nbr, *spair;
    const float *embed, *rw1, *rb1, *rw2, *rb2, *ew1, *eb1, *ew2, *eb2;
    const float *mix, *emix, *hw1, *hb1, *hw2, *hb2, *lw, *lb;
    float *rbf, *hbuf, *G0, *V;
    int   *cnt, *off, *cur, *nbrs, *specs, *wk;
    float *out;
};

__global__ __launch_bounds__(TPB, 2) void fused(Params P)
{
    cg::grid_group grid = cg::this_grid();
    const int t    = threadIdx.x;
    const int gsz  = gridDim.x * TPB;
    const int gid  = blockIdx.x * TPB + t;
    const int lane = t & 63, wb = t >> 6;

    __shared__ union SM {
        int   scan[256];
        float H[4][4][RH];                       // f0: [wave][spec][j]
        struct { float a[8][KD]; float b[8][KD]; } hd;
    } sm;

    // ---- P0: zero counters -------------------------------------------------
    for (int i = gid; i < kAtoms; i += gsz) P.cnt[i] = 0;
    if (gid < 8) P.wk[gid] = 0;
    grid.sync();

    // ---- P1: histogram -----------------------------------------------------
    for (int p = gid; p < kPairs; p += gsz) atomicAdd(&P.cnt[P.ctr[p]], 1);
    grid.sync();

    // ---- P2: exclusive scan (block 0) -------------------------------------
    if (blockIdx.x == 0) {
        const int CH = 20;                       // 256*20 = 5120 >= 5000
        int base = t * CH, loc[CH], run = 0;
        #pragma unroll
        for (int i = 0; i < CH; i++) {
            int idx = base + i;
            int v = (idx < kAtoms) ? P.cnt[idx] : 0;
            loc[i] = run; run += v;
        }
        sm.scan[t] = run; __syncthreads();
        for (int st = 1; st < 256; st <<= 1) {
            int v = (t >= st) ? sm.scan[t - st] : 0;
            __syncthreads(); sm.scan[t] += v; __syncthreads();
        }
        int excl = t ? sm.scan[t - 1] : 0;
        #pragma unroll
        for (int i = 0; i < CH; i++) {
            int idx = base + i;
            if (idx < kAtoms) { P.off[idx] = excl + loc[i]; P.cur[idx] = excl + loc[i]; }
        }
        if (t == 255) P.off[kAtoms] = sm.scan[255];
    }
    grid.sync();

    // ---- P3: build rbf, h2 (erad hidden), nbrs, specs ----------------------
    for (int p = gid; p < kPairs; p += gsz) {
        int ci = P.ctr[p], ni = P.nbr[p], sp = P.spair[p];
        float s0 = (float)P.shifts[p*3+0] - 1.0f;
        float s1 = (float)P.shifts[p*3+1] - 1.0f;
        float s2 = (float)P.shifts[p*3+2] - 1.0f;
        const float* C = P.cells + sp * 9;
        float vx = P.pos[ni*3+0]-P.pos[ci*3+0]+s0*C[0]+s1*C[3]+s2*C[6];
        float vy = P.pos[ni*3+1]-P.pos[ci*3+1]+s0*C[1]+s1*C[4]+s2*C[7];
        float vz = P.pos[ni*3+2]-P.pos[ci*3+2]+s0*C[2]+s1*C[5]+s2*C[8];
        float d = sqrtf(vx*vx + vy*vy + vz*vz + 1e-12f);
        float fcut = (d < kCutoff) ? 0.5f*(__cosf(kPi*d/kCutoff)+1.0f) : 0.0f;
        float r[NB];
        #pragma unroll
        for (int i = 0; i < NB; i++) {
            float tt = d - (kCutoff/(NB-1))*(float)i;
            r[i] = __expf(-2.0f*tt*tt)*fcut;
        }
        int slot = atomicAdd(&P.cur[ci], 1);
        P.nbrs[slot]  = ni;
        P.specs[slot] = P.species[ni];
        float4* rdst = (float4*)(P.rbf + (size_t)slot*NB);
        rdst[0] = make_float4(r[0],r[1],r[2],r[3]);
        rdst[1] = make_float4(r[4],r[5],r[6],r[7]);
        float* hdst = P.hbuf + (size_t)slot*RH;
        #pragma unroll
        for (int jq = 0; jq < RH/4; jq++) {
            float4 hv; float* pv = (float*)&hv;
            #pragma unroll
            for (int u = 0; u < 4; u++) {
                int j = 4*jq + u;
                float acc = P.eb1[j];
                #pragma unroll
                for (int i = 0; i < NB; i++) acc += r[i]*P.ew1[i*RH+j];
                pv[u] = silu(acc);
            }
            *(float4*)(hdst + 4*jq) = hv;
        }
    }
    grid.sync();

    // ---- P4: f0 -> G0 (dynamic per-wave atoms) -----------------------------
    {
        int g = lane >> 5, j = lane & 31;
        float w1c[NB];
        #pragma unroll
        for (int i = 0; i < NB; i++) w1c[i] = P.rw1[i*RH+j];
        float b1j = P.rb1[j];
        for (;;) {
            int a; if (lane == 0) a = atomicAdd(&P.wk[0], 1);
            a = __shfl(a, 0);
            if (a >= kAtoms) break;
            int start = __builtin_amdgcn_readfirstlane(P.off[a]);
            int end   = __builtin_amdgcn_readfirstlane(P.off[a+1]);
            int m = end - start;
            float H0=0,H1=0,H2=0,H3=0; int n0=0,n1=0,n2=0,n3=0;
            for (int pr = g; pr < m; pr += 2) {
                const float* rb = P.rbf + (size_t)(start+pr)*NB;
                float acc = b1j;
                #pragma unroll
                for (int i = 0; i < NB; i++) acc += rb[i]*w1c[i];
                float h = silu(acc);
                int s = P.specs[start+pr];
                H0 += (s==0)?h:0.0f; H1 += (s==1)?h:0.0f;
                H2 += (s==2)?h:0.0f; H3 += (s==3)?h:0.0f;
                n0 += (s==0); n1 += (s==1); n2 += (s==2); n3 += (s==3);
            }
            H0 += __shfl_xor(H0,32); H1 += __shfl_xor(H1,32);
            H2 += __shfl_xor(H2,32); H3 += __shfl_xor(H3,32);
            n0 += __shfl_xor(n0,32); n1 += __shfl_xor(n1,32);
            n2 += __shfl_xor(n2,32); n3 += __shfl_xor(n3,32);
            if (lane < 32) {
                sm.H[wb][0][j]=H0; sm.H[wb][1][j]=H1;
                sm.H[wb][2][j]=H2; sm.H[wb][3][j]=H3;
            }
            __builtin_amdgcn_wave_barrier();
            float fn0=(float)n0, fn1=(float)n1, fn2=(float)n2, fn3=(float)n3;
            #pragma unroll
            for (int half = 0; half < 2; half++) {
                int k = lane + 64*half;
                float e0=P.embed[0*KD+k], e1=P.embed[1*KD+k];
                float e2=P.embed[2*KD+k], e3=P.embed[3*KD+k];
                float Q0=0,Q1=0,Q2=0,Q3=0;
                #pragma unroll
                for (int jq = 0; jq < RH/4; jq++) {
                    float4 h0=*(const float4*)&sm.H[wb][0][4*jq];
                    float4 h1=*(const float4*)&sm.H[wb][1][4*jq];
                    float4 h2=*(const float4*)&sm.H[wb][2][4*jq];
                    float4 h3=*(const float4*)&sm.H[wb][3][4*jq];
                    float wa=P.rw2[(4*jq+0)*(3*KD)+k], wbv=P.rw2[(4*jq+1)*(3*KD)+k];
                    float wc=P.rw2[(4*jq+2)*(3*KD)+k], wd=P.rw2[(4*jq+3)*(3*KD)+k];
                    Q0 += h0.x*wa+h0.y*wbv+h0.z*wc+h0.w*wd;
                    Q1 += h1.x*wa+h1.y*wbv+h1.z*wc+h1.w*wd;
                    Q2 += h2.x*wa+h2.y*wbv+h2.z*wc+h2.w*wd;
                    Q3 += h3.x*wa+h3.y*wbv+h3.z*wc+h3.w*wd;
                }
                float F = P.rb2[k]*(fn0*e0+fn1*e1+fn2*e2+fn3*e3)
                        + e0*Q0 + e1*Q1 + e2*Q2 + e3*Q3;
                float F0v = C1*F;
                P.G0[(size_t)a*KD+k] = F0v + F0v*F0v*P.mix[k];
            }
            __builtin_amdgcn_wave_barrier();
        }
    }
    grid.sync();

    // ---- P5: d0 -> V (scalar h2 reads, float2 gathers, nbr prefetch) -------
    {
        int k0 = 2*lane, k1 = 2*lane + 1;
        float w2e0[RH], w2e1[RH];
        #pragma unroll
        for (int j = 0; j < RH; j++) {
            w2e0[j] = P.ew2[j*(3*KD)+k0];
            w2e1[j] = P.ew2[j*(3*KD)+k1];
        }
        float b2k0 = P.eb2[k0], b2k1 = P.eb2[k1];
        float ex0  = P.emix[k0], ex1 = P.emix[k1];
        for (;;) {
            int a; if (lane == 0) a = atomicAdd(&P.wk[1], 1);
            a = __shfl(a, 0);
            if (a >= kAtoms) break;
            int start = __builtin_amdgcn_readfirstlane(P.off[a]);
            int end   = __builtin_amdgcn_readfirstlane(P.off[a+1]);
            int m = end - start;
            float D0 = 0.0f, D1 = 0.0f;
            int nb_cur = (m > 0) ? __builtin_amdgcn_readfirstlane(P.nbrs[start]) : 0;
            #pragma unroll 2
            for (int i = 0; i < m; i++) {
                int nb_next = (i+1 < m) ? __builtin_amdgcn_readfirstlane(P.nbrs[start+i+1]) : 0;
                const float2 gv = *(const float2*)(P.G0 + (size_t)nb_cur*KD + k0);
                const float* h = P.hbuf + (size_t)(start+i)*RH;  // wave-uniform -> s_load
                float R0 = b2k0, R1 = b2k1;
                #pragma unroll
                for (int j = 0; j < RH; j++) {
                    float hj = h[j];
                    R0 += hj*w2e0[j]; R1 += hj*w2e1[j];
                }
                D0 += R0*gv.x; D1 += R1*gv.y;
                nb_cur = nb_next;
            }
            float2 ga = *(const float2*)(P.G0 + (size_t)a*KD + k0);
            float q0 = ga.x + C2*D0, q1 = ga.y + C2*D1;
            float2 vo; vo.x = q0 + q0*q0*ex0; vo.y = q1 + q1*q1*ex1;
            *(float2*)(P.V + (size_t)a*KD + k0) = vo;
        }
    }
    grid.sync();

    // ---- P6: head MLP (8-atom tiles, 2 halves x 128 j) ---------------------
    {
        int j = t & 127, half = t >> 7;
        float lb0 = P.lb[0];
        for (int tile = blockIdx.x; tile < kAtoms/8; tile += gridDim.x) {
            int abase = tile*8;
            __syncthreads();
            #pragma unroll
            for (int q = 0; q < 4; q++) {
                int a = half*4 + q;
                sm.hd.a[a][j] = P.V[(size_t)(abase+a)*KD + j];
            }
            __syncthreads();
            float acc[4]; float b1j = P.hb1[j];
            #pragma unroll
            for (int q = 0; q < 4; q++) acc[q] = b1j;
            for (int kk = 0; kk < KD; kk += 4) {
                float wa=P.hw1[(kk+0)*KD+j], wbv=P.hw1[(kk+1)*KD+j];
                float wc=P.hw1[(kk+2)*KD+j], wd=P.hw1[(kk+3)*KD+j];
                #pragma unroll
                for (int q = 0; q < 4; q++) {
                    float4 v = *(const float4*)&sm.hd.a[half*4+q][kk];
                    acc[q] += v.x*wa + v.y*wbv + v.z*wc + v.w*wd;
                }
            }
            #pragma unroll
            for (int q = 0; q < 4; q++) sm.hd.b[half*4+q][j] = silu(acc[q]);
            __syncthreads();
            float b2j = P.hb2[j];
            #pragma unroll
            for (int q = 0; q < 4; q++) acc[q] = b2j;
            for (int kk = 0; kk < KD; kk += 4) {
                float wa=P.hw2[(kk+0)*KD+j], wbv=P.hw2[(kk+1)*KD+j];
                float wc=P.hw2[(kk+2)*KD+j], wd=P.hw2[(kk+3)*KD+j];
                #pragma unroll
                for (int q = 0; q < 4; q++) {
                    float4 v = *(const float4*)&sm.hd.b[half*4+q][kk];
                    acc[q] += v.x*wa + v.y*wbv + v.z*wc + v.w*wd;
                }
            }
            float lwj = P.lw[j];
            __syncthreads();
            #pragma unroll
            for (int q = 0; q < 4; q++) sm.hd.a[half*4+q][j] = silu(acc[q])*lwj;
            __syncthreads();
            for (int s = 64; s > 0; s >>= 1) {
                if (j < s) {
                    #pragma unroll
                    for (int q = 0; q < 4; q++)
                        sm.hd.a[half*4+q][j] += sm.hd.a[half*4+q][j+s];
                }
                __syncthreads();
            }
            if (t < 8) P.out[abase+t] = sm.hd.a[t][0] + lb0;
        }
    }
}

// ---------------------------------------------------------------------------
extern "C" void kernel_launch(void* const* d_in, const int* in_sizes, int n_in,
                              void* d_out, int out_size, void* d_ws, size_t ws_size,
                              hipStream_t stream) {
    Params P;
    P.pos     = (const float*)d_in[0];
    P.cells   = (const float*)d_in[1];
    P.species = (const int*)d_in[2];
    P.shifts  = (const int*)d_in[3];
    P.ctr     = (const int*)d_in[4];
    P.nbr     = (const int*)d_in[5];
    P.spair   = (const int*)d_in[6];
    P.embed   = (const float*)d_in[7];
    P.rw1     = (const float*)d_in[8];
    P.rb1     = (const float*)d_in[9];
    P.rw2     = (const float*)d_in[10];
    P.rb2     = (const float*)d_in[11];
    P.ew1     = (const float*)d_in[12];
    P.eb1     = (const float*)d_in[13];
    P.ew2     = (const float*)d_in[14];
    P.eb2     = (const float*)d_in[15];
    P.mix     = (const float*)d_in[16];
    P.emix    = (const float*)d_in[17];
    P.hw1     = (const float*)d_in[18];
    P.hb1     = (const float*)d_in[19];
    P.hw2     = (const float*)d_in[20];
    P.hb2     = (const float*)d_in[21];
    P.lw      = (const float*)d_in[22];
    P.lb      = (const float*)d_in[23];
    // U2 (d_in[24]) unused: l>=1 channels are dead code for the output.

    float* f = (float*)d_ws;
    P.rbf  = f;                                  // 160000*8   = 5.12 MB
    P.hbuf = P.rbf + (size_t)kPairs*NB;          // 160000*32  = 20.48 MB
    P.G0   = P.hbuf + (size_t)kPairs*RH;         // 5000*128
    P.V    = P.G0 + (size_t)kAtoms*KD;           // 5000*128
    int* ip = (int*)(P.V + (size_t)kAtoms*KD);
    P.cnt  = ip;             ip += kAtoms;
    P.off  = ip;             ip += kAtoms + 1;
    P.cur  = ip;             ip += kAtoms;
    P.nbrs = ip;             ip += kPairs;
    P.specs= ip;             ip += kPairs;
    P.wk   = ip;
    P.out  = (float*)d_out;

    void* kargs[] = { &P };
    hipError_t e = hipLaunchCooperativeKernel((const void*)fused,
                                              dim3(BLOCKS), dim3(TPB),
                                              kargs, 0, stream);
    if (e != hipSuccess) {
        // conservative fallback: 1 block/CU is always co-resident
        hipLaunchCooperativeKernel((const void*)fused,
                                   dim3(256), dim3(TPB), kargs, 0, stream);
    }
}

// Round 9
// 233.037 us; speedup vs baseline: 3.4442x; 3.4442x over previous
//
#include <hip/hip_runtime.h>

// Problem constants
constexpr int   kAtoms  = 5000;
constexpr int   kPairs  = 160000;
constexpr int   KD      = 128;   // K
constexpr int   NB      = 8;     // N_BASIS
constexpr int   RH      = 32;    // RAD_HIDDEN
constexpr float kCutoff = 5.0f;
constexpr float kPi     = 3.14159265358979323846f;
constexpr float C1 = 0.2f * 0.1767767f;   // INIT_SCALE * MSG_SCALE
constexpr float C2 = 1.2f * 0.1767767f;   // (1+INIT_SCALE) * MSG_SCALE

__device__ __forceinline__ float silu(float x) { return x / (1.0f + __expf(-x)); }
__device__ __forceinline__ void wave_fence() { __builtin_amdgcn_wave_barrier(); }

// Only the l=0 channel reaches the output; l>=1 / sph / U2 are dead code.
//   F0[a][k] = C1 * sum_p R0_p[k]*e_spec[k];  G0 = F0+F0^2*mix
//   D[a][k]  = sum_p Re0_p[k]*G0[nbr_p][k];   n = G0+C2*D;  V = n+n^2*emix
//   out = head MLP(V)
// Structure: hist -> scan -> build(rbf + erad-hidden h2) -> f0 -> d0+head.

// ---------------------------------------------------------------------------
__global__ __launch_bounds__(256) void hist_kernel(
    const int* __restrict__ ctr, int* __restrict__ cnt)
{
    int p = blockIdx.x * 256 + threadIdx.x;
    atomicAdd(cnt + ctr[p], 1);
}

// ---------------------------------------------------------------------------
__global__ __launch_bounds__(1024) void scan_kernel(
    const int* __restrict__ cnt, int* __restrict__ off, int* __restrict__ cur)
{
    __shared__ int s_part[1024];
    const int CH = 5;                       // 1024*5 = 5120 >= 5000
    int t = threadIdx.x;
    int base = t * CH;
    int loc[CH];
    int run = 0;
    #pragma unroll
    for (int i = 0; i < CH; i++) {
        int idx = base + i;
        int v = (idx < kAtoms) ? cnt[idx] : 0;
        loc[i] = run;
        run += v;
    }
    s_part[t] = run;
    __syncthreads();
    for (int st = 1; st < 1024; st <<= 1) {
        int v = (t >= st) ? s_part[t - st] : 0;
        __syncthreads();
        s_part[t] += v;
        __syncthreads();
    }
    int excl = (t > 0) ? s_part[t - 1] : 0;
    #pragma unroll
    for (int i = 0; i < CH; i++) {
        int idx = base + i;
        if (idx < kAtoms) { off[idx] = excl + loc[i]; cur[idx] = excl + loc[i]; }
    }
    if (t == 1023) off[kAtoms] = s_part[1023];
}

// ---------------------------------------------------------------------------
// Build: geometry -> rbf (for f0) and erad hidden h2 (for d0), CSR order.
// ---------------------------------------------------------------------------
__global__ __launch_bounds__(256) void build_kernel(
    const float* __restrict__ pos, const float* __restrict__ cells,
    const int* __restrict__ species, const int* __restrict__ shifts,
    const int* __restrict__ ctr, const int* __restrict__ nbr,
    const int* __restrict__ spair,
    const float* __restrict__ ew1, const float* __restrict__ eb1,
    int* __restrict__ cur, int* __restrict__ nbrs_s, int* __restrict__ specs_s,
    float* __restrict__ rbf_s, float* __restrict__ hbuf)
{
    int p = blockIdx.x * 256 + threadIdx.x;
    int ci = ctr[p], ni = nbr[p], sp = spair[p];
    float s0 = (float)shifts[p * 3 + 0] - 1.0f;
    float s1 = (float)shifts[p * 3 + 1] - 1.0f;
    float s2 = (float)shifts[p * 3 + 2] - 1.0f;
    const float* C = cells + sp * 9;
    float vx = pos[ni * 3 + 0] - pos[ci * 3 + 0] + s0 * C[0] + s1 * C[3] + s2 * C[6];
    float vy = pos[ni * 3 + 1] - pos[ci * 3 + 1] + s0 * C[1] + s1 * C[4] + s2 * C[7];
    float vz = pos[ni * 3 + 2] - pos[ci * 3 + 2] + s0 * C[2] + s1 * C[5] + s2 * C[8];
    float d = sqrtf(vx * vx + vy * vy + vz * vz + 1e-12f);
    float fcut = (d < kCutoff) ? 0.5f * (__cosf(kPi * d / kCutoff) + 1.0f) : 0.0f;

    int slot = atomicAdd(cur + ci, 1);
    nbrs_s[slot]  = ni;
    specs_s[slot] = species[ni];

    float r[NB];
    #pragma unroll
    for (int i = 0; i < NB; i++) {
        float tt = d - (kCutoff / (NB - 1)) * (float)i;
        r[i] = __expf(-2.0f * tt * tt) * fcut;
    }
    float4* rdst = (float4*)(rbf_s + (size_t)slot * NB);
    rdst[0] = make_float4(r[0], r[1], r[2], r[3]);
    rdst[1] = make_float4(r[4], r[5], r[6], r[7]);

    // erad hidden layer for this pair (d0 consumes via uniform reads)
    float* hdst = hbuf + (size_t)slot * RH;
    #pragma unroll
    for (int jq = 0; jq < RH / 4; jq++) {
        float4 hv; float* pv = (float*)&hv;
        #pragma unroll
        for (int u = 0; u < 4; u++) {
            int j = 4 * jq + u;
            float acc = eb1[j];
            #pragma unroll
            for (int i = 0; i < NB; i++) acc += r[i] * ew1[i * RH + j];
            pv[u] = silu(acc);
        }
        *(float4*)(hdst + 4 * jq) = hv;
    }
}

// ---------------------------------------------------------------------------
// K4: species-factored F0 + G0. 256 thr = 4 waves, wave = one atom. (R7 ver.)
// ---------------------------------------------------------------------------
__global__ __launch_bounds__(256) void f0_kernel(
    const float* __restrict__ rbf_s, const int* __restrict__ specs_s,
    const int* __restrict__ off,
    const float* __restrict__ embed,
    const float* __restrict__ w1, const float* __restrict__ b1,
    const float* __restrict__ w2, const float* __restrict__ b2,
    const float* __restrict__ mix,
    float* __restrict__ G0)
{
    __shared__ float s_w1[NB][RH];
    __shared__ float s_b1v[RH];
    __shared__ float s_H[4][2][4][RH];   // [wave][g][spec][j]
    __shared__ float s_Hc[4][4][RH];     // [wave][spec][j]
    __shared__ float s_n[4][2][4];

    int t = threadIdx.x, w = t >> 6, lane = t & 63;
    for (int idx = t; idx < NB * RH; idx += 256)
        s_w1[idx >> 5][idx & 31] = w1[idx];
    if (t < RH) s_b1v[t] = b1[t];
    __syncthreads();

    int a = blockIdx.x * 4 + w;          // 5000 = 4*1250
    int start = off[a], m = off[a + 1] - start;

    int g = lane >> 5, j = lane & 31;
    float H0 = 0, H1 = 0, H2 = 0, H3 = 0;
    int   n0 = 0, n1 = 0, n2 = 0, n3 = 0;
    float b1j = s_b1v[j];
    for (int pr = g; pr < m; pr += 2) {
        const float* rb = rbf_s + (size_t)(start + pr) * NB;
        float acc = b1j;
        #pragma unroll
        for (int i = 0; i < NB; i++) acc += rb[i] * s_w1[i][j];
        float h = silu(acc);
        int s = specs_s[start + pr];
        H0 += (s == 0) ? h : 0.0f;  H1 += (s == 1) ? h : 0.0f;
        H2 += (s == 2) ? h : 0.0f;  H3 += (s == 3) ? h : 0.0f;
        n0 += (s == 0); n1 += (s == 1); n2 += (s == 2); n3 += (s == 3);
    }
    s_H[w][g][0][j] = H0; s_H[w][g][1][j] = H1;
    s_H[w][g][2][j] = H2; s_H[w][g][3][j] = H3;
    if (j == 0) {
        s_n[w][g][0] = (float)n0; s_n[w][g][1] = (float)n1;
        s_n[w][g][2] = (float)n2; s_n[w][g][3] = (float)n3;
    }
    wave_fence();
    #pragma unroll
    for (int e = lane; e < 4 * RH; e += 64) {
        int s = e >> 5, jj = e & 31;
        s_Hc[w][s][jj] = s_H[w][0][s][jj] + s_H[w][1][s][jj];
    }
    wave_fence();
    float nc0 = s_n[w][0][0] + s_n[w][1][0];
    float nc1 = s_n[w][0][1] + s_n[w][1][1];
    float nc2 = s_n[w][0][2] + s_n[w][1][2];
    float nc3 = s_n[w][0][3] + s_n[w][1][3];

    #pragma unroll
    for (int half = 0; half < 2; half++) {
        int k = lane + 64 * half;
        float e0 = embed[0 * KD + k], e1 = embed[1 * KD + k];
        float e2 = embed[2 * KD + k], e3 = embed[3 * KD + k];
        float P0 = 0, P1 = 0, P2 = 0, P3 = 0;
        #pragma unroll
        for (int jq = 0; jq < RH / 4; jq++) {
            float4 h0 = *(const float4*)&s_Hc[w][0][4 * jq];
            float4 h1 = *(const float4*)&s_Hc[w][1][4 * jq];
            float4 h2 = *(const float4*)&s_Hc[w][2][4 * jq];
            float4 h3 = *(const float4*)&s_Hc[w][3][4 * jq];
            float wa = w2[(4 * jq + 0) * (3 * KD) + k];
            float wb = w2[(4 * jq + 1) * (3 * KD) + k];
            float wc = w2[(4 * jq + 2) * (3 * KD) + k];
            float wd = w2[(4 * jq + 3) * (3 * KD) + k];
            P0 += h0.x * wa + h0.y * wb + h0.z * wc + h0.w * wd;
            P1 += h1.x * wa + h1.y * wb + h1.z * wc + h1.w * wd;
            P2 += h2.x * wa + h2.y * wb + h2.z * wc + h2.w * wd;
            P3 += h3.x * wa + h3.y * wb + h3.z * wc + h3.w * wd;
        }
        float F = b2[k] * (nc0 * e0 + nc1 * e1 + nc2 * e2 + nc3 * e3)
                + e0 * P0 + e1 * P1 + e2 * P2 + e3 * P3;
        float F0v = C1 * F;
        G0[(size_t)a * KD + k] = F0v + F0v * F0v * mix[k];
    }
}

// ---------------------------------------------------------------------------
// K5: d0 + head fused. 256 thr = 4 waves; wave = one atom (lane = k pair
// 2*lane, 2*lane+1). h2 read with wave-uniform addresses (no LDS staging,
// no launch-bounds register cap -> no spills). Then head MLP on the 4 atoms.
// ---------------------------------------------------------------------------
__global__ void d0head_kernel(
    const float* __restrict__ hbuf, const int* __restrict__ nbrs_s,
    const int* __restrict__ off,
    const float* __restrict__ w2, const float* __restrict__ b2,
    const float* __restrict__ emix,
    const float* __restrict__ G0,
    const float* __restrict__ hw1, const float* __restrict__ hb1,
    const float* __restrict__ hw2, const float* __restrict__ hb2,
    const float* __restrict__ lw, const float* __restrict__ lb,
    float* __restrict__ out)
{
    __shared__ float s_v[4][KD];
    __shared__ float s_m[4][KD];

    int t = threadIdx.x, w = t >> 6, lane = t & 63;
    int a = blockIdx.x * 4 + w;
    int start = __builtin_amdgcn_readfirstlane(off[a]);
    int end   = __builtin_amdgcn_readfirstlane(off[a + 1]);

    int k0 = 2 * lane, k1 = 2 * lane + 1;
    float w2c0[RH], w2c1[RH];
    #pragma unroll
    for (int j = 0; j < RH; j++) {
        float2 wv = *(const float2*)&w2[j * (3 * KD) + k0];
        w2c0[j] = wv.x; w2c1[j] = wv.y;
    }
    float b2k0 = b2[k0], b2k1 = b2[k1];

    float D0 = 0.0f, D1 = 0.0f;
    for (int i = start; i < end; i++) {
        int nb = __builtin_amdgcn_readfirstlane(nbrs_s[i]);
        const float* h = hbuf + (size_t)i * RH;         // wave-uniform
        float2 gv = *(const float2*)(G0 + (size_t)nb * KD + k0);
        float4 h4[RH / 4];
        #pragma unroll
        for (int q = 0; q < RH / 4; q++) h4[q] = *(const float4*)(h + 4 * q);
        float R0 = b2k0, R1 = b2k1;
        #pragma unroll
        for (int q = 0; q < RH / 4; q++) {
            R0 += h4[q].x * w2c0[4*q+0] + h4[q].y * w2c0[4*q+1]
                + h4[q].z * w2c0[4*q+2] + h4[q].w * w2c0[4*q+3];
            R1 += h4[q].x * w2c1[4*q+0] + h4[q].y * w2c1[4*q+1]
                + h4[q].z * w2c1[4*q+2] + h4[q].w * w2c1[4*q+3];
        }
        D0 += R0 * gv.x;
        D1 += R1 * gv.y;
    }
    {
        float2 ga = *(const float2*)(G0 + (size_t)a * KD + k0);
        float q0 = ga.x + C2 * D0, q1 = ga.y + C2 * D1;
        s_v[w][k0] = q0 + q0 * q0 * emix[k0];
        s_v[w][k1] = q1 + q1 * q1 * emix[k1];
    }
    __syncthreads();

    // ---- head: 2 thread-groups x 128 j; group handles 2 atoms -------------
    int j = t & 127, grp = t >> 7;
    int a0 = grp * 2, a1 = grp * 2 + 1;
    float acc0 = hb1[j], acc1 = acc0;
    for (int kk = 0; kk < KD; kk += 4) {
        float wa = hw1[(kk+0)*KD+j], wb = hw1[(kk+1)*KD+j];
        float wc = hw1[(kk+2)*KD+j], wd = hw1[(kk+3)*KD+j];
        float4 v0 = *(const float4*)&s_v[a0][kk];
        float4 v1 = *(const float4*)&s_v[a1][kk];
        acc0 += v0.x*wa + v0.y*wb + v0.z*wc + v0.w*wd;
        acc1 += v1.x*wa + v1.y*wb + v1.z*wc + v1.w*wd;
    }
    s_m[a0][j] = silu(acc0);
    s_m[a1][j] = silu(acc1);
    __syncthreads();
    acc0 = hb2[j]; acc1 = acc0;
    for (int kk = 0; kk < KD; kk += 4) {
        float wa = hw2[(kk+0)*KD+j], wb = hw2[(kk+1)*KD+j];
        float wc = hw2[(kk+2)*KD+j], wd = hw2[(kk+3)*KD+j];
        float4 v0 = *(const float4*)&s_m[a0][kk];
        float4 v1 = *(const float4*)&s_m[a1][kk];
        acc0 += v0.x*wa + v0.y*wb + v0.z*wc + v0.w*wd;
        acc1 += v1.x*wa + v1.y*wb + v1.z*wc + v1.w*wd;
    }
    float lwj = lw[j];
    __syncthreads();
    s_v[a0][j] = silu(acc0) * lwj;
    s_v[a1][j] = silu(acc1) * lwj;
    __syncthreads();
    for (int s = 64; s > 0; s >>= 1) {
        if (j < s) {
            s_v[a0][j] += s_v[a0][j + s];
            s_v[a1][j] += s_v[a1][j + s];
        }
        __syncthreads();
    }
    if (t < 4) out[blockIdx.x * 4 + t] = s_v[t][0] + lb[0];
}

// ---------------------------------------------------------------------------
extern "C" void kernel_launch(void* const* d_in, const int* in_sizes, int n_in,
                              void* d_out, int out_size, void* d_ws, size_t ws_size,
                              hipStream_t stream) {
    const float* positions = (const float*)d_in[0];
    const float* cells     = (const float*)d_in[1];
    const int*   species   = (const int*)d_in[2];
    const int*   shifts    = (const int*)d_in[3];
    const int*   ctr       = (const int*)d_in[4];
    const int*   nbr       = (const int*)d_in[5];
    const int*   spair     = (const int*)d_in[6];
    const float* embed     = (const float*)d_in[7];
    const float* rad_w1    = (const float*)d_in[8];
    const float* rad_b1    = (const float*)d_in[9];
    const float* rad_w2    = (const float*)d_in[10];
    const float* rad_b2    = (const float*)d_in[11];
    const float* erad_w1   = (const float*)d_in[12];
    const float* erad_b1   = (const float*)d_in[13];
    const float* erad_w2   = (const float*)d_in[14];
    const float* erad_b2   = (const float*)d_in[15];
    const float* mix_a     = (const float*)d_in[16];
    const float* emix_a    = (const float*)d_in[17];
    const float* head_w1   = (const float*)d_in[18];
    const float* head_b1   = (const float*)d_in[19];
    const float* head_w2   = (const float*)d_in[20];
    const float* head_b2   = (const float*)d_in[21];
    const float* last_w    = (const float*)d_in[22];
    const float* last_b    = (const float*)d_in[23];
    // U2 (d_in[24]) unused: l>=1 channels are dead code for the output.

    float* rbf_s = (float*)d_ws;                          // 160000*8  = 5.12 MB
    float* hbuf  = rbf_s + (size_t)kPairs * NB;           // 160000*32 = 20.48 MB
    float* G0    = hbuf + (size_t)kPairs * RH;            // 5000*128
    int*   cnt   = (int*)(G0 + (size_t)kAtoms * KD);      // 5000
    int*   off   = cnt + kAtoms;                          // 5001
    int*   cur   = off + kAtoms + 1;                      // 5000
    int*   nbrs  = cur + kAtoms;                          // 160000
    int*   specs = nbrs + kPairs;                         // 160000

    hipMemsetAsync(cnt, 0, kAtoms * sizeof(int), stream);

    hist_kernel<<<kPairs / 256, 256, 0, stream>>>(ctr, cnt);
    scan_kernel<<<1, 1024, 0, stream>>>(cnt, off, cur);
    build_kernel<<<kPairs / 256, 256, 0, stream>>>(
        positions, cells, species, shifts, ctr, nbr, spair,
        erad_w1, erad_b1, cur, nbrs, specs, rbf_s, hbuf);

    f0_kernel<<<kAtoms / 4, 256, 0, stream>>>(
        rbf_s, specs, off, embed, rad_w1, rad_b1, rad_w2, rad_b2,
        mix_a, G0);

    d0head_kernel<<<kAtoms / 4, 256, 0, stream>>>(
        hbuf, nbrs, off, erad_w2, erad_b2, emix_a, G0,
        head_w1, head_b1, head_w2, head_b2, last_w, last_b,
        (float*)d_out);
}